// Round 2
// baseline (817.819 us; speedup 1.0000x reference)
//
#include <hip/hip_runtime.h>
#include <stdint.h>

#define NN 100000
#define NE 1600000

// ---------------- CSR build ----------------
// edge_index arrives as int32 (harness converts all integer inputs to int),
// layout [2, NE] row-major: src = ei[e], dst = ei[NE + e].

__global__ void k_count(const int* __restrict__ ei, int* __restrict__ cnt) {
    int e = blockIdx.x * blockDim.x + threadIdx.x;
    if (e < NE) {
        int d = ei[NE + e];
        atomicAdd(&cnt[d], 1);
    }
}

// inclusive scan of 512-element chunks, in place; block totals to partial[]
__global__ __launch_bounds__(512) void k_scan1(int* __restrict__ data,
                                               int* __restrict__ partial, int n) {
    __shared__ int s[512];
    int t = threadIdx.x;
    int i = blockIdx.x * 512 + t;
    int v = (i < n) ? data[i] : 0;
    s[t] = v;
    __syncthreads();
    #pragma unroll
    for (int off = 1; off < 512; off <<= 1) {
        int tmp = (t >= off) ? s[t - off] : 0;
        __syncthreads();
        s[t] += tmp;
        __syncthreads();
    }
    if (i < n) data[i] = s[t];
    if (t == 511) partial[blockIdx.x] = s[511];
}

__global__ void k_scan3(const int* __restrict__ incl, const int* __restrict__ partial,
                        int* __restrict__ row_ptr, int* __restrict__ cursor, int n) {
    int i = blockIdx.x * blockDim.x + threadIdx.x;
    if (i < n) {
        int b = i >> 9;
        int off = b ? partial[b - 1] : 0;
        int v = incl[i] + off;
        row_ptr[i + 1] = v;
        cursor[i + 1] = v;
        if (i == 0) { row_ptr[0] = 0; cursor[0] = 0; }
    }
}

__global__ void k_fill(const int* __restrict__ ei, int* __restrict__ cursor,
                       int* __restrict__ csr) {
    int e = blockIdx.x * blockDim.x + threadIdx.x;
    if (e < NE) {
        int d = ei[NE + e];
        int s = ei[e];
        int pos = atomicAdd(&cursor[d], 1);
        csr[pos] = s;
    }
}

// ---------------- mean aggregation (gather) ----------------
// one wave per node; 128 feats = float2 per lane

__global__ __launch_bounds__(256) void k_agg_mean(const float* __restrict__ feat,
                                                  const int* __restrict__ row_ptr,
                                                  const int* __restrict__ csr,
                                                  float* __restrict__ out) {
    int node = blockIdx.x * 4 + (threadIdx.x >> 6);
    if (node >= NN) return;
    int lane = threadIdx.x & 63;
    int beg = row_ptr[node];
    int end = row_ptr[node + 1];
    float sx = 0.f, sy = 0.f;
    for (int e = beg; e < end; ++e) {
        int s = csr[e];
        float2 v = *(const float2*)&feat[(size_t)s * 128 + lane * 2];
        sx += v.x;
        sy += v.y;
    }
    int deg = end - beg;
    float inv = 1.0f / (float)(deg > 1 ? deg : 1);
    float2 o;
    o.x = sx * inv;
    o.y = sy * inv;
    *(float2*)&out[(size_t)node * 128 + lane * 2] = o;
}

// ---------------- fused SGEMM: C = [A0|A1] @ [W0|W1]^T + bias (opt relu) ----
// A0,A1: [M,128]; W0,W1: [Ntot,128]; K = 256 total. 64x64 tile, 256 thr,
// 4x4 acc per thread. LDS padded stride 68: float4-aligned rows, <=2-way
// read conflicts.

__global__ __launch_bounds__(256) void k_gemm_cat(
    const float* __restrict__ A0, const float* __restrict__ A1,
    const float* __restrict__ W0, const float* __restrict__ W1,
    const float* __restrict__ bias, float* __restrict__ C,
    int M, int Ntot, int relu) {
    __shared__ float As[64][68];
    __shared__ float Ws[64][68];
    int m0 = blockIdx.x * 64;
    int n0 = blockIdx.y * 64;
    int tid = threadIdx.x;
    int lrow = tid >> 4;          // 0..15
    int lc4 = (tid & 15) * 4;     // 0..60
    int ty = tid >> 4;
    int tx = tid & 15;
    float acc[4][4] = {};

    for (int k0 = 0; k0 < 256; k0 += 64) {
        const float* Ab = (k0 < 128) ? A0 : A1;
        const float* Wb = (k0 < 128) ? W0 : W1;
        int kk = k0 & 127;
        #pragma unroll
        for (int p = 0; p < 4; ++p) {
            int m = m0 + p * 16 + lrow;
            float4 v = make_float4(0.f, 0.f, 0.f, 0.f);
            if (m < M) v = *(const float4*)&Ab[(size_t)m * 128 + kk + lc4];
            As[lc4 + 0][p * 16 + lrow] = v.x;
            As[lc4 + 1][p * 16 + lrow] = v.y;
            As[lc4 + 2][p * 16 + lrow] = v.z;
            As[lc4 + 3][p * 16 + lrow] = v.w;
        }
        #pragma unroll
        for (int p = 0; p < 4; ++p) {
            int n = n0 + p * 16 + lrow;
            float4 v = make_float4(0.f, 0.f, 0.f, 0.f);
            if (n < Ntot) v = *(const float4*)&Wb[(size_t)n * 128 + kk + lc4];
            Ws[lc4 + 0][p * 16 + lrow] = v.x;
            Ws[lc4 + 1][p * 16 + lrow] = v.y;
            Ws[lc4 + 2][p * 16 + lrow] = v.z;
            Ws[lc4 + 3][p * 16 + lrow] = v.w;
        }
        __syncthreads();
        #pragma unroll
        for (int k = 0; k < 64; ++k) {
            float4 av = *(const float4*)&As[k][ty * 4];
            float4 bv = *(const float4*)&Ws[k][tx * 4];
            float a[4] = {av.x, av.y, av.z, av.w};
            float b[4] = {bv.x, bv.y, bv.z, bv.w};
            #pragma unroll
            for (int i = 0; i < 4; ++i)
                #pragma unroll
                for (int j = 0; j < 4; ++j)
                    acc[i][j] += a[i] * b[j];
        }
        __syncthreads();
    }

    bool full = (m0 + 64 <= M) && (n0 + 64 <= Ntot);
    if (full) {
        #pragma unroll
        for (int i = 0; i < 4; ++i) {
            int m = m0 + ty * 4 + i;
            int n = n0 + tx * 4;
            float4 v;
            v.x = acc[i][0] + bias[n + 0];
            v.y = acc[i][1] + bias[n + 1];
            v.z = acc[i][2] + bias[n + 2];
            v.w = acc[i][3] + bias[n + 3];
            if (relu) {
                v.x = fmaxf(v.x, 0.f); v.y = fmaxf(v.y, 0.f);
                v.z = fmaxf(v.z, 0.f); v.w = fmaxf(v.w, 0.f);
            }
            *(float4*)&C[(size_t)m * Ntot + n] = v;
        }
    } else {
        #pragma unroll
        for (int i = 0; i < 4; ++i) {
            int m = m0 + ty * 4 + i;
            if (m >= M) continue;
            #pragma unroll
            for (int j = 0; j < 4; ++j) {
                int n = n0 + tx * 4 + j;
                if (n >= Ntot) continue;
                float v = acc[i][j] + bias[n];
                if (relu) v = fmaxf(v, 0.f);
                C[(size_t)m * Ntot + n] = v;
            }
        }
    }
}

// ---------------- launch ----------------

extern "C" void kernel_launch(void* const* d_in, const int* in_sizes, int n_in,
                              void* d_out, int out_size, void* d_ws, size_t ws_size,
                              hipStream_t stream) {
    const float* x   = (const float*)d_in[0];
    const int* ei    = (const int*)d_in[1];   // int32! harness converts integer inputs
    const float* Wl1 = (const float*)d_in[2];
    const float* bl1 = (const float*)d_in[3];
    const float* Wr1 = (const float*)d_in[4];
    const float* Wl2 = (const float*)d_in[5];
    const float* bl2 = (const float*)d_in[6];
    const float* Wr2 = (const float*)d_in[7];
    float* out = (float*)d_out;

    char* ws = (char*)d_ws;
    size_t off = 0;
    auto alloc = [&](size_t bytes) -> char* {
        char* p = ws + off;
        off = (off + bytes + 511) & ~(size_t)511;
        return p;
    };
    int* cnt      = (int*)alloc((size_t)NN * 4);
    int* row_ptr  = (int*)alloc((size_t)(NN + 1) * 4);
    int* cursor   = (int*)alloc((size_t)(NN + 1) * 4);
    int* partial  = (int*)alloc(1024 * 4);
    int* partial2 = (int*)alloc(1024 * 4);
    int* csr      = (int*)alloc((size_t)NE * 4);
    float* aggx   = (float*)alloc((size_t)NN * 128 * 4);
    float* h      = (float*)alloc((size_t)NN * 128 * 4);
    if (off > ws_size) return;  // ws too small: leave output poisoned (visible failure)

    // CSR build
    hipMemsetAsync(cnt, 0, (size_t)NN * 4, stream);
    k_count<<<(NE + 255) / 256, 256, 0, stream>>>(ei, cnt);
    int NB1 = (NN + 511) / 512;
    k_scan1<<<NB1, 512, 0, stream>>>(cnt, partial, NN);
    k_scan1<<<1, 512, 0, stream>>>(partial, partial2, NB1);
    k_scan3<<<(NN + 255) / 256, 256, 0, stream>>>(cnt, partial, row_ptr, cursor, NN);
    k_fill<<<(NE + 255) / 256, 256, 0, stream>>>(ei, cursor, csr);

    // layer 1: aggx = mean(x[src]); h = relu([aggx|x] @ [Wl1|Wr1]^T + bl1)
    k_agg_mean<<<(NN + 3) / 4, 256, 0, stream>>>(x, row_ptr, csr, aggx);
    dim3 g1((NN + 63) / 64, 2);
    k_gemm_cat<<<g1, 256, 0, stream>>>(aggx, x, Wl1, Wr1, bl1, h, NN, 128, 1);

    // layer 2: aggx = mean(h[src]); out = [aggx|h] @ [Wl2|Wr2]^T + bl2
    k_agg_mean<<<(NN + 3) / 4, 256, 0, stream>>>(h, row_ptr, csr, aggx);
    dim3 g2((NN + 63) / 64, 1);
    k_gemm_cat<<<g2, 256, 0, stream>>>(aggx, h, Wl2, Wr2, bl2, out, NN, 40, 0);
}

// Round 3
// 500.004 us; speedup vs baseline: 1.6356x; 1.6356x over previous
//
#include <hip/hip_runtime.h>
#include <stdint.h>

#define NN 100000
#define NE 1600000

typedef _Float16 half8 __attribute__((ext_vector_type(8)));
typedef _Float16 half4 __attribute__((ext_vector_type(4)));
typedef float f32x4 __attribute__((ext_vector_type(4)));

__device__ inline float2 unpack_h2(unsigned v) {
    union { unsigned u; _Float16 h[2]; } c; c.u = v;
    return make_float2((float)c.h[0], (float)c.h[1]);
}
__device__ inline unsigned pack_h2(float a, float b) {
    union { unsigned u; _Float16 h[2]; } c;
    c.h[0] = (_Float16)a; c.h[1] = (_Float16)b; return c.u;
}

// ---------------- CSR build (edge_index is int32 from harness) ----------------

__global__ void k_count(const int* __restrict__ ei, int* __restrict__ cnt) {
    int e = blockIdx.x * blockDim.x + threadIdx.x;
    if (e < NE) atomicAdd(&cnt[ei[NE + e]], 1);
}

__global__ __launch_bounds__(512) void k_scan1(int* __restrict__ data,
                                               int* __restrict__ partial, int n) {
    __shared__ int s[512];
    int t = threadIdx.x;
    int i = blockIdx.x * 512 + t;
    int v = (i < n) ? data[i] : 0;
    s[t] = v;
    __syncthreads();
    #pragma unroll
    for (int off = 1; off < 512; off <<= 1) {
        int tmp = (t >= off) ? s[t - off] : 0;
        __syncthreads();
        s[t] += tmp;
        __syncthreads();
    }
    if (i < n) data[i] = s[t];
    if (t == 511) partial[blockIdx.x] = s[511];
}

__global__ void k_scan3(const int* __restrict__ incl, const int* __restrict__ partial,
                        int* __restrict__ row_ptr, int* __restrict__ cursor, int n) {
    int i = blockIdx.x * blockDim.x + threadIdx.x;
    if (i < n) {
        int b = i >> 9;
        int off = b ? partial[b - 1] : 0;
        int v = incl[i] + off;
        row_ptr[i + 1] = v;
        cursor[i + 1] = v;
        if (i == 0) { row_ptr[0] = 0; cursor[0] = 0; }
    }
}

__global__ void k_fill(const int* __restrict__ ei, int* __restrict__ cursor,
                       int* __restrict__ csr) {
    int e = blockIdx.x * blockDim.x + threadIdx.x;
    if (e < NE) {
        int d = ei[NE + e];
        int s = ei[e];
        int pos = atomicAdd(&cursor[d], 1);
        csr[pos] = s;
    }
}

// ---------------- weight prep: f32 -> fp16, concat [Wl;Wr] ----------------

__global__ void k_prep_w(const float* __restrict__ Wl1, const float* __restrict__ Wr1,
                         const float* __restrict__ Wl2, const float* __restrict__ Wr2,
                         _Float16* __restrict__ Wc1, _Float16* __restrict__ Wc2) {
    int i = blockIdx.x * 256 + threadIdx.x;
    if (i < 16384) {  // 128*128
        Wc1[i] = (_Float16)Wl1[i];
        Wc1[16384 + i] = (_Float16)Wr1[i];
    }
    if (i < 5120) {   // 40*128
        Wc2[i] = (_Float16)Wl2[i];
        Wc2[5120 + i] = (_Float16)Wr2[i];
    }
}

// ---------------- fp16 MFMA GEMM: C = A @ W^T, K=128 ----------------
// A: [M,128] f32 (A_F32=1) or fp16 (A_F32=0); W: [Ntot,128] fp16 row-major.
// C: [M,Ntot] fp16. 64-row tile per block, loops Ntot in 64-col chunks.
// LDS stride 136 fp16 (272 B): 16B-aligned b128 frag reads, 2-way conflicts (free).

template <int A_F32>
__global__ __launch_bounds__(256) void k_gemm(const void* __restrict__ Av,
                                              const _Float16* __restrict__ W,
                                              _Float16* __restrict__ C,
                                              int M, int Ntot) {
    __shared__ _Float16 As[64][136];
    __shared__ _Float16 Ws[64][136];
    int tid = threadIdx.x;
    int m0 = blockIdx.x * 64;

    if (A_F32) {
        const float* A = (const float*)Av;
        #pragma unroll
        for (int it = 0; it < 8; ++it) {
            int idx = it * 1024 + tid * 4;
            int r = idx >> 7, c = idx & 127;
            float4 v = make_float4(0.f, 0.f, 0.f, 0.f);
            if (m0 + r < M) v = *(const float4*)&A[(size_t)(m0 + r) * 128 + c];
            half4 hv;
            hv[0] = (_Float16)v.x; hv[1] = (_Float16)v.y;
            hv[2] = (_Float16)v.z; hv[3] = (_Float16)v.w;
            *(half4*)&As[r][c] = hv;
        }
    } else {
        const _Float16* A = (const _Float16*)Av;
        #pragma unroll
        for (int it = 0; it < 4; ++it) {
            int idx = it * 2048 + tid * 8;
            int r = idx >> 7, c = idx & 127;
            half8 v = {};
            if (m0 + r < M) v = *(const half8*)&A[(size_t)(m0 + r) * 128 + c];
            *(half8*)&As[r][c] = v;
        }
    }

    int wave = tid >> 6, lane = tid & 63;
    int wm = (wave >> 1) * 32, wn = (wave & 1) * 32;
    int lrow = lane & 15, kblk = lane >> 4;

    for (int nc0 = 0; nc0 < Ntot; nc0 += 64) {
        __syncthreads();
        #pragma unroll
        for (int it = 0; it < 4; ++it) {
            int idx = it * 2048 + tid * 8;
            int r = idx >> 7, c = idx & 127;
            half8 v = {};
            if (nc0 + r < Ntot) v = *(const half8*)&W[(size_t)(nc0 + r) * 128 + c];
            *(half8*)&Ws[r][c] = v;
        }
        __syncthreads();

        f32x4 acc00 = {0.f,0.f,0.f,0.f}, acc01 = {0.f,0.f,0.f,0.f};
        f32x4 acc10 = {0.f,0.f,0.f,0.f}, acc11 = {0.f,0.f,0.f,0.f};
        #pragma unroll
        for (int ks = 0; ks < 4; ++ks) {
            half8 a0 = *(const half8*)&As[wm + lrow][ks * 32 + kblk * 8];
            half8 a1 = *(const half8*)&As[wm + 16 + lrow][ks * 32 + kblk * 8];
            half8 b0 = *(const half8*)&Ws[wn + lrow][ks * 32 + kblk * 8];
            half8 b1 = *(const half8*)&Ws[wn + 16 + lrow][ks * 32 + kblk * 8];
            acc00 = __builtin_amdgcn_mfma_f32_16x16x32_f16(a0, b0, acc00, 0, 0, 0);
            acc01 = __builtin_amdgcn_mfma_f32_16x16x32_f16(a0, b1, acc01, 0, 0, 0);
            acc10 = __builtin_amdgcn_mfma_f32_16x16x32_f16(a1, b0, acc10, 0, 0, 0);
            acc11 = __builtin_amdgcn_mfma_f32_16x16x32_f16(a1, b1, acc11, 0, 0, 0);
        }

        // C/D layout: col = lane&15, row = (lane>>4)*4 + reg  [m89-verified]
        int rbase = kblk * 4;
        #pragma unroll
        for (int r = 0; r < 4; ++r) {
            int gr0 = m0 + wm + rbase + r;
            int gr1 = m0 + wm + 16 + rbase + r;
            int gc0 = nc0 + wn + lrow;
            int gc1 = nc0 + wn + 16 + lrow;
            if (gr0 < M && gc0 < Ntot) C[(size_t)gr0 * Ntot + gc0] = (_Float16)acc00[r];
            if (gr0 < M && gc1 < Ntot) C[(size_t)gr0 * Ntot + gc1] = (_Float16)acc01[r];
            if (gr1 < M && gc0 < Ntot) C[(size_t)gr1 * Ntot + gc0] = (_Float16)acc10[r];
            if (gr1 < M && gc1 < Ntot) C[(size_t)gr1 * Ntot + gc1] = (_Float16)acc11[r];
        }
    }
}

// ---------------- fused agg layer 1 ----------------
// tmp1: [NN][256] fp16 (cols 0-127 = xl = x@Wl1^T, 128-255 = xr = x@Wr1^T)
// h[node] = relu(mean(xl[src]) + bl1 + xr[node]), stored fp16 [NN][128]

__global__ __launch_bounds__(256) void k_agg1(const _Float16* __restrict__ tmp1,
                                              const float* __restrict__ bl1,
                                              const int* __restrict__ row_ptr,
                                              const int* __restrict__ csr,
                                              _Float16* __restrict__ h) {
    int node = blockIdx.x * 4 + (threadIdx.x >> 6);
    if (node >= NN) return;
    int lane = threadIdx.x & 63;
    int beg = row_ptr[node], end = row_ptr[node + 1];
    const unsigned* p = (const unsigned*)tmp1;  // row = 128 uints; xl = uints 0..63
    float sx = 0.f, sy = 0.f;
    int e = beg;
    for (; e + 4 <= end; e += 4) {
        int s0 = csr[e], s1 = csr[e + 1], s2 = csr[e + 2], s3 = csr[e + 3];
        unsigned v0 = p[(size_t)s0 * 128 + lane];
        unsigned v1 = p[(size_t)s1 * 128 + lane];
        unsigned v2 = p[(size_t)s2 * 128 + lane];
        unsigned v3 = p[(size_t)s3 * 128 + lane];
        float2 f0 = unpack_h2(v0), f1 = unpack_h2(v1);
        float2 f2 = unpack_h2(v2), f3 = unpack_h2(v3);
        sx += (f0.x + f1.x) + (f2.x + f3.x);
        sy += (f0.y + f1.y) + (f2.y + f3.y);
    }
    for (; e < end; ++e) {
        int s = csr[e];
        float2 f = unpack_h2(p[(size_t)s * 128 + lane]);
        sx += f.x; sy += f.y;
    }
    int deg = end - beg;
    float inv = 1.0f / (float)(deg > 1 ? deg : 1);
    float2 xr = unpack_h2(p[(size_t)node * 128 + 64 + lane]);
    float2 b = *(const float2*)&bl1[lane * 2];
    float o0 = fmaxf(sx * inv + b.x + xr.x, 0.f);
    float o1 = fmaxf(sy * inv + b.y + xr.y, 0.f);
    ((unsigned*)h)[(size_t)node * 64 + lane] = pack_h2(o0, o1);
}

// ---------------- fused agg layer 2 ----------------
// tmp2: [NN][80] fp16 (cols 0-39 = hl = h@Wl2^T, 40-79 = hr = h@Wr2^T)
// out[node] = mean(hl[src]) + bl2 + hr[node], f32 [NN][40]
// 2 nodes per wave (half-wave each, lanes 0-19 of each half active)

__global__ __launch_bounds__(256) void k_agg2(const _Float16* __restrict__ tmp2,
                                              const float* __restrict__ bl2,
                                              const int* __restrict__ row_ptr,
                                              const int* __restrict__ csr,
                                              float* __restrict__ out) {
    int tid = threadIdx.x;
    int wave = tid >> 6, lane = tid & 63;
    int hw = lane >> 5, ln = lane & 31;
    int node = blockIdx.x * 8 + wave * 2 + hw;
    bool act = (node < NN) && (ln < 20);
    int beg = 0, end = 0;
    if (node < NN) { beg = row_ptr[node]; end = row_ptr[node + 1]; }
    const unsigned* p = (const unsigned*)tmp2;  // row = 40 uints; hl = 0..19
    float sx = 0.f, sy = 0.f;
    for (int e = beg; e < end; ++e) {
        int s = csr[e];
        if (act) {
            float2 f = unpack_h2(p[(size_t)s * 40 + ln]);
            sx += f.x; sy += f.y;
        }
    }
    if (act) {
        int deg = end - beg;
        float inv = 1.0f / (float)(deg > 1 ? deg : 1);
        float2 hr = unpack_h2(p[(size_t)node * 40 + 20 + ln]);
        float2 b = *(const float2*)&bl2[ln * 2];
        float2 o;
        o.x = sx * inv + b.x + hr.x;
        o.y = sy * inv + b.y + hr.y;
        *(float2*)&out[(size_t)node * 40 + ln * 2] = o;
    }
}

// ---------------- launch ----------------

extern "C" void kernel_launch(void* const* d_in, const int* in_sizes, int n_in,
                              void* d_out, int out_size, void* d_ws, size_t ws_size,
                              hipStream_t stream) {
    const float* x   = (const float*)d_in[0];
    const int* ei    = (const int*)d_in[1];   // int32 (harness converts ints)
    const float* Wl1 = (const float*)d_in[2];
    const float* bl1 = (const float*)d_in[3];
    const float* Wr1 = (const float*)d_in[4];
    const float* Wl2 = (const float*)d_in[5];
    const float* bl2 = (const float*)d_in[6];
    const float* Wr2 = (const float*)d_in[7];
    float* out = (float*)d_out;

    char* ws = (char*)d_ws;
    size_t off = 0;
    auto alloc = [&](size_t bytes) -> char* {
        char* pp = ws + off;
        off = (off + bytes + 511) & ~(size_t)511;
        return pp;
    };
    int* cnt       = (int*)alloc((size_t)NN * 4);
    int* row_ptr   = (int*)alloc((size_t)(NN + 1) * 4);
    int* cursor    = (int*)alloc((size_t)(NN + 1) * 4);
    int* partial   = (int*)alloc(1024 * 4);
    int* partial2  = (int*)alloc(1024 * 4);
    int* csr       = (int*)alloc((size_t)NE * 4);
    _Float16* Wc1  = (_Float16*)alloc((size_t)256 * 128 * 2);
    _Float16* Wc2  = (_Float16*)alloc((size_t)80 * 128 * 2);
    _Float16* tmp1 = (_Float16*)alloc((size_t)NN * 256 * 2);
    _Float16* h    = (_Float16*)alloc((size_t)NN * 128 * 2);
    _Float16* tmp2 = (_Float16*)alloc((size_t)NN * 80 * 2);
    if (off > ws_size) return;

    // CSR build
    hipMemsetAsync(cnt, 0, (size_t)NN * 4, stream);
    k_count<<<(NE + 255) / 256, 256, 0, stream>>>(ei, cnt);
    int NB1 = (NN + 511) / 512;
    k_scan1<<<NB1, 512, 0, stream>>>(cnt, partial, NN);
    k_scan1<<<1, 512, 0, stream>>>(partial, partial2, NB1);
    k_scan3<<<(NN + 255) / 256, 256, 0, stream>>>(cnt, partial, row_ptr, cursor, NN);
    k_fill<<<(NE + 255) / 256, 256, 0, stream>>>(ei, cursor, csr);

    // weights -> fp16 concat
    k_prep_w<<<64, 256, 0, stream>>>(Wl1, Wr1, Wl2, Wr2, Wc1, Wc2);

    int gm = (NN + 63) / 64;
    // layer 1: tmp1 = x @ [Wl1;Wr1]^T  (K=128, N=256)
    k_gemm<1><<<gm, 256, 0, stream>>>(x, Wc1, tmp1, NN, 256);
    // h = relu(mean(xl[src]) + bl1 + xr)
    k_agg1<<<(NN + 3) / 4, 256, 0, stream>>>(tmp1, bl1, row_ptr, csr, h);
    // layer 2: tmp2 = h @ [Wl2;Wr2]^T  (K=128, N=80)
    k_gemm<0><<<gm, 256, 0, stream>>>(h, Wc2, tmp2, NN, 80);
    // out = mean(hl[src]) + bl2 + hr
    k_agg2<<<(NN + 7) / 8, 256, 0, stream>>>(tmp2, bl2, row_ptr, csr, out);
}

// Round 7
// 366.445 us; speedup vs baseline: 2.2318x; 1.3645x over previous
//
#include <hip/hip_runtime.h>
#include <stdint.h>

#define NN 100000
#define NE 1600000
#define NBLK 256                      // histogram / scatter blocks
#define BSH 7                         // bucket shift: 128 nodes per bucket
#define NBUK ((NN + 127) >> 7)        // 782 buckets
#define NH (NBUK * NBLK)              // 200192 count-matrix entries

typedef _Float16 half8 __attribute__((ext_vector_type(8)));
typedef _Float16 half4 __attribute__((ext_vector_type(4)));
typedef float f32x4 __attribute__((ext_vector_type(4)));

__device__ inline float2 unpack_h2(unsigned v) {
    union { unsigned u; _Float16 h[2]; } c; c.u = v;
    return make_float2((float)c.h[0], (float)c.h[1]);
}
__device__ inline unsigned pack_h2(float a, float b) {
    union { unsigned u; _Float16 h[2]; } c;
    c.h[0] = (_Float16)a; c.h[1] = (_Float16)b; return c.u;
}

// ============ atomic-free CSR build ============
// edge_index is int32 from harness: src = ei[e], dst = ei[NE+e].
// Bucket = dst>>7. Count matrix histM[bucket][block] -> bucket-major exclusive
// scan -> contiguous (bucket,block) segments; bucket regions contiguous.

__global__ __launch_bounds__(256) void k_hist(const int* __restrict__ ei,
                                              int* __restrict__ histM) {
    __shared__ int h[NBUK];
    for (int i = threadIdx.x; i < NBUK; i += 256) h[i] = 0;
    __syncthreads();
    int blk = blockIdx.x;
    int chunk = (NE + NBLK - 1) / NBLK;
    int beg = blk * chunk;
    int end = beg + chunk < NE ? beg + chunk : NE;
    for (int e = beg + threadIdx.x; e < end; e += 256)
        atomicAdd(&h[ei[NE + e] >> BSH], 1);           // LDS atomic
    __syncthreads();
    for (int b = threadIdx.x; b < NBUK; b += 256)
        histM[b * NBLK + blk] = h[b];
}

// inclusive scan of 512-chunks in place; block totals to partial[]
__global__ __launch_bounds__(512) void k_scan1(int* __restrict__ data,
                                               int* __restrict__ partial, int n) {
    __shared__ int s[512];
    int t = threadIdx.x;
    int i = blockIdx.x * 512 + t;
    int v = (i < n) ? data[i] : 0;
    s[t] = v;
    __syncthreads();
    #pragma unroll
    for (int off = 1; off < 512; off <<= 1) {
        int tmp = (t >= off) ? s[t - off] : 0;
        __syncthreads();
        s[t] += tmp;
        __syncthreads();
    }
    if (i < n) data[i] = s[t];
    if (t == 511) partial[blockIdx.x] = s[511];
}

__global__ void k_scanout(const int* __restrict__ incl, const int* __restrict__ partial,
                          int* __restrict__ offM, int n) {
    int i = blockIdx.x * blockDim.x + threadIdx.x;
    if (i < n) {
        int b = i >> 9;
        int off = b ? partial[b - 1] : 0;
        offM[i + 1] = incl[i] + off;
        if (i == 0) offM[0] = 0;
    }
}

// scatter edges into bucket segments; pairs packed (src<<7)|dstLocal (24 bits)
__global__ __launch_bounds__(256) void k_scatter(const int* __restrict__ ei,
                                                 const int* __restrict__ offM,
                                                 unsigned* __restrict__ pairs) {
    __shared__ int cur[NBUK];
    int blk = blockIdx.x;
    for (int b = threadIdx.x; b < NBUK; b += 256)
        cur[b] = offM[b * NBLK + blk];
    __syncthreads();
    int chunk = (NE + NBLK - 1) / NBLK;
    int beg = blk * chunk;
    int end = beg + chunk < NE ? beg + chunk : NE;
    for (int e = beg + threadIdx.x; e < end; e += 256) {
        int d = ei[NE + e];
        int s = ei[e];
        int pos = atomicAdd(&cur[d >> BSH], 1);        // LDS atomic
        pairs[pos] = ((unsigned)s << BSH) | (unsigned)(d & 127);
    }
}

// per-bucket: group edges by exact node -> csr + row_ptr
__global__ __launch_bounds__(256) void k_csr(const unsigned* __restrict__ pairs,
                                             const int* __restrict__ offM,
                                             int* __restrict__ csr,
                                             int* __restrict__ row_ptr) {
    __shared__ int cnt[128], off[129], cur[128];
    int b = blockIdx.x;
    int t = threadIdx.x;
    int ebeg = offM[b * NBLK];
    int eend = (b + 1 < NBUK) ? offM[(b + 1) * NBLK] : NE;
    if (t < 128) cnt[t] = 0;
    __syncthreads();
    for (int e = ebeg + t; e < eend; e += 256)
        atomicAdd(&cnt[pairs[e] & 127], 1);
    __syncthreads();
    if (t == 0) {
        int acc = 0;
        for (int i = 0; i < 128; ++i) { off[i] = acc; acc += cnt[i]; }
        off[128] = acc;
    }
    __syncthreads();
    if (t < 128) cur[t] = 0;
    __syncthreads();
    for (int e = ebeg + t; e < eend; e += 256) {
        unsigned p = pairs[e];
        int local = p & 127;
        int lpos = atomicAdd(&cur[local], 1);
        csr[ebeg + off[local] + lpos] = (int)(p >> BSH);
    }
    int n0 = b << BSH;
    if (t < 128 && n0 + t < NN) row_ptr[n0 + t] = ebeg + off[t];
    if (b == 0 && t == 0) row_ptr[NN] = NE;
}

// ============ weight prep: f32 -> fp16, concat [Wl;Wr] ============

__global__ void k_prep_w(const float* __restrict__ Wl1, const float* __restrict__ Wr1,
                         const float* __restrict__ Wl2, const float* __restrict__ Wr2,
                         _Float16* __restrict__ Wc1, _Float16* __restrict__ Wc2) {
    int i = blockIdx.x * 256 + threadIdx.x;
    if (i < 16384) {
        Wc1[i] = (_Float16)Wl1[i];
        Wc1[16384 + i] = (_Float16)Wr1[i];
    }
    if (i < 5120) {
        Wc2[i] = (_Float16)Wl2[i];
        Wc2[5120 + i] = (_Float16)Wr2[i];
    }
}

// ============ fp16 MFMA GEMM: C = A @ W^T, K=128 ============
// A: [M,128] f32 (A_F32=1) or fp16; W: [Ntot,128] fp16; C: [M,Ntot] fp16.

template <int A_F32>
__global__ __launch_bounds__(256) void k_gemm(const void* __restrict__ Av,
                                              const _Float16* __restrict__ W,
                                              _Float16* __restrict__ C,
                                              int M, int Ntot) {
    __shared__ _Float16 As[64][136];
    __shared__ _Float16 Ws[64][136];
    int tid = threadIdx.x;
    int m0 = blockIdx.x * 64;

    if (A_F32) {
        const float* A = (const float*)Av;
        #pragma unroll
        for (int it = 0; it < 8; ++it) {
            int idx = it * 1024 + tid * 4;
            int r = idx >> 7, c = idx & 127;
            float4 v = make_float4(0.f, 0.f, 0.f, 0.f);
            if (m0 + r < M) v = *(const float4*)&A[(size_t)(m0 + r) * 128 + c];
            half4 hv;
            hv[0] = (_Float16)v.x; hv[1] = (_Float16)v.y;
            hv[2] = (_Float16)v.z; hv[3] = (_Float16)v.w;
            *(half4*)&As[r][c] = hv;
        }
    } else {
        const _Float16* A = (const _Float16*)Av;
        #pragma unroll
        for (int it = 0; it < 4; ++it) {
            int idx = it * 2048 + tid * 8;
            int r = idx >> 7, c = idx & 127;
            half8 v = {};
            if (m0 + r < M) v = *(const half8*)&A[(size_t)(m0 + r) * 128 + c];
            *(half8*)&As[r][c] = v;
        }
    }

    int wave = tid >> 6, lane = tid & 63;
    int wm = (wave >> 1) * 32, wn = (wave & 1) * 32;
    int lrow = lane & 15, kblk = lane >> 4;

    for (int nc0 = 0; nc0 < Ntot; nc0 += 64) {
        __syncthreads();
        #pragma unroll
        for (int it = 0; it < 4; ++it) {
            int idx = it * 2048 + tid * 8;
            int r = idx >> 7, c = idx & 127;
            half8 v = {};
            if (nc0 + r < Ntot) v = *(const half8*)&W[(size_t)(nc0 + r) * 128 + c];
            *(half8*)&Ws[r][c] = v;
        }
        __syncthreads();

        f32x4 acc00 = {0.f,0.f,0.f,0.f}, acc01 = {0.f,0.f,0.f,0.f};
        f32x4 acc10 = {0.f,0.f,0.f,0.f}, acc11 = {0.f,0.f,0.f,0.f};
        #pragma unroll
        for (int ks = 0; ks < 4; ++ks) {
            half8 a0 = *(const half8*)&As[wm + lrow][ks * 32 + kblk * 8];
            half8 a1 = *(const half8*)&As[wm + 16 + lrow][ks * 32 + kblk * 8];
            half8 b0 = *(const half8*)&Ws[wn + lrow][ks * 32 + kblk * 8];
            half8 b1 = *(const half8*)&Ws[wn + 16 + lrow][ks * 32 + kblk * 8];
            acc00 = __builtin_amdgcn_mfma_f32_16x16x32_f16(a0, b0, acc00, 0, 0, 0);
            acc01 = __builtin_amdgcn_mfma_f32_16x16x32_f16(a0, b1, acc01, 0, 0, 0);
            acc10 = __builtin_amdgcn_mfma_f32_16x16x32_f16(a1, b0, acc10, 0, 0, 0);
            acc11 = __builtin_amdgcn_mfma_f32_16x16x32_f16(a1, b1, acc11, 0, 0, 0);
        }

        int rbase = kblk * 4;
        #pragma unroll
        for (int r = 0; r < 4; ++r) {
            int gr0 = m0 + wm + rbase + r;
            int gr1 = m0 + wm + 16 + rbase + r;
            int gc0 = nc0 + wn + lrow;
            int gc1 = nc0 + wn + 16 + lrow;
            if (gr0 < M && gc0 < Ntot) C[(size_t)gr0 * Ntot + gc0] = (_Float16)acc00[r];
            if (gr0 < M && gc1 < Ntot) C[(size_t)gr0 * Ntot + gc1] = (_Float16)acc01[r];
            if (gr1 < M && gc0 < Ntot) C[(size_t)gr1 * Ntot + gc0] = (_Float16)acc10[r];
            if (gr1 < M && gc1 < Ntot) C[(size_t)gr1 * Ntot + gc1] = (_Float16)acc11[r];
        }
    }
}

// ============ fused agg layer 1 ============
// tmp1: [NN][256] fp16 (xl | xr). h = relu(mean(xl[src]) + bl1 + xr), fp16.

__global__ __launch_bounds__(256) void k_agg1(const _Float16* __restrict__ tmp1,
                                              const float* __restrict__ bl1,
                                              const int* __restrict__ row_ptr,
                                              const int* __restrict__ csr,
                                              _Float16* __restrict__ h) {
    int node = blockIdx.x * 4 + (threadIdx.x >> 6);
    if (node >= NN) return;
    int lane = threadIdx.x & 63;
    int beg = row_ptr[node], end = row_ptr[node + 1];
    const unsigned* p = (const unsigned*)tmp1;
    float sx = 0.f, sy = 0.f;
    int e = beg;
    for (; e + 4 <= end; e += 4) {
        int s0 = csr[e], s1 = csr[e + 1], s2 = csr[e + 2], s3 = csr[e + 3];
        float2 f0 = unpack_h2(p[(size_t)s0 * 128 + lane]);
        float2 f1 = unpack_h2(p[(size_t)s1 * 128 + lane]);
        float2 f2 = unpack_h2(p[(size_t)s2 * 128 + lane]);
        float2 f3 = unpack_h2(p[(size_t)s3 * 128 + lane]);
        sx += (f0.x + f1.x) + (f2.x + f3.x);
        sy += (f0.y + f1.y) + (f2.y + f3.y);
    }
    for (; e < end; ++e) {
        float2 f = unpack_h2(p[(size_t)csr[e] * 128 + lane]);
        sx += f.x; sy += f.y;
    }
    int deg = end - beg;
    float inv = 1.0f / (float)(deg > 1 ? deg : 1);
    float2 xr = unpack_h2(p[(size_t)node * 128 + 64 + lane]);
    float2 b = *(const float2*)&bl1[lane * 2];
    float o0 = fmaxf(sx * inv + b.x + xr.x, 0.f);
    float o1 = fmaxf(sy * inv + b.y + xr.y, 0.f);
    ((unsigned*)h)[(size_t)node * 64 + lane] = pack_h2(o0, o1);
}

// ============ fused agg layer 2 ============
// tmp2: [NN][80] fp16 (hl | hr). out = mean(hl[src]) + bl2 + hr, f32.

__global__ __launch_bounds__(256) void k_agg2(const _Float16* __restrict__ tmp2,
                                              const float* __restrict__ bl2,
                                              const int* __restrict__ row_ptr,
                                              const int* __restrict__ csr,
                                              float* __restrict__ out) {
    int tid = threadIdx.x;
    int wave = tid >> 6, lane = tid & 63;
    int hw = lane >> 5, ln = lane & 31;
    int node = blockIdx.x * 8 + wave * 2 + hw;
    bool act = (node < NN) && (ln < 20);
    int beg = 0, end = 0;
    if (node < NN) { beg = row_ptr[node]; end = row_ptr[node + 1]; }
    const unsigned* p = (const unsigned*)tmp2;
    float sx = 0.f, sy = 0.f;
    for (int e = beg; e < end; ++e) {
        int s = csr[e];
        if (act) {
            float2 f = unpack_h2(p[(size_t)s * 40 + ln]);
            sx += f.x; sy += f.y;
        }
    }
    if (act) {
        int deg = end - beg;
        float inv = 1.0f / (float)(deg > 1 ? deg : 1);
        float2 hr = unpack_h2(p[(size_t)node * 40 + 20 + ln]);
        float2 b = *(const float2*)&bl2[ln * 2];
        float2 o;
        o.x = sx * inv + b.x + hr.x;
        o.y = sy * inv + b.y + hr.y;
        *(float2*)&out[(size_t)node * 40 + ln * 2] = o;
    }
}

// ============ launch ============

extern "C" void kernel_launch(void* const* d_in, const int* in_sizes, int n_in,
                              void* d_out, int out_size, void* d_ws, size_t ws_size,
                              hipStream_t stream) {
    const float* x   = (const float*)d_in[0];
    const int* ei    = (const int*)d_in[1];   // int32 (harness converts ints)
    const float* Wl1 = (const float*)d_in[2];
    const float* bl1 = (const float*)d_in[3];
    const float* Wr1 = (const float*)d_in[4];
    const float* Wl2 = (const float*)d_in[5];
    const float* bl2 = (const float*)d_in[6];
    const float* Wr2 = (const float*)d_in[7];
    float* out = (float*)d_out;

    char* ws = (char*)d_ws;
    size_t off = 0;
    auto alloc = [&](size_t bytes) -> char* {
        char* pp = ws + off;
        off = (off + bytes + 511) & ~(size_t)511;
        return pp;
    };
    int* histM      = (int*)alloc((size_t)NH * 4);
    int* offM       = (int*)alloc((size_t)(NH + 1) * 4);
    int* partial    = (int*)alloc(1024 * 4);
    int* partial2   = (int*)alloc(1024 * 4);
    unsigned* pairs = (unsigned*)alloc((size_t)NE * 4);
    int* csr        = (int*)alloc((size_t)NE * 4);
    int* row_ptr    = (int*)alloc((size_t)(NN + 1) * 4);
    _Float16* Wc1   = (_Float16*)alloc((size_t)256 * 128 * 2);
    _Float16* Wc2   = (_Float16*)alloc((size_t)80 * 128 * 2);
    _Float16* tmp1  = (_Float16*)alloc((size_t)NN * 256 * 2);
    _Float16* h     = (_Float16*)alloc((size_t)NN * 128 * 2);
    _Float16* tmp2  = (_Float16*)alloc((size_t)NN * 80 * 2);
    if (off > ws_size) return;

    // CSR build (no global atomics)
    k_hist<<<NBLK, 256, 0, stream>>>(ei, histM);
    int NSB = (NH + 511) / 512;                       // 391
    k_scan1<<<NSB, 512, 0, stream>>>(histM, partial, NH);
    k_scan1<<<1, 512, 0, stream>>>(partial, partial2, NSB);
    k_scanout<<<(NH + 255) / 256, 256, 0, stream>>>(histM, partial, offM, NH);
    k_scatter<<<NBLK, 256, 0, stream>>>(ei, offM, pairs);
    k_csr<<<NBUK, 256, 0, stream>>>(pairs, offM, csr, row_ptr);

    // weights -> fp16 concat
    k_prep_w<<<64, 256, 0, stream>>>(Wl1, Wr1, Wl2, Wr2, Wc1, Wc2);

    int gm = (NN + 63) / 64;
    // layer 1: tmp1 = x @ [Wl1;Wr1]^T  (K=128, N=256)
    k_gemm<1><<<gm, 256, 0, stream>>>(x, Wc1, tmp1, NN, 256);
    // h = relu(mean(xl[src]) + bl1 + xr)
    k_agg1<<<(NN + 3) / 4, 256, 0, stream>>>(tmp1, bl1, row_ptr, csr, h);
    // layer 2: tmp2 = h @ [Wl2;Wr2]^T  (K=128, N=80)
    k_gemm<0><<<gm, 256, 0, stream>>>(h, Wc2, tmp2, NN, 80);
    // out = mean(hl[src]) + bl2 + hr
    k_agg2<<<(NN + 7) / 8, 256, 0, stream>>>(tmp2, bl2, row_ptr, csr, out);
}

// Round 9
// 305.768 us; speedup vs baseline: 2.6746x; 1.1984x over previous
//
#include <hip/hip_runtime.h>
#include <stdint.h>

#define NN 100000
#define NE 1600000
#define NBLK 256                      // histogram / scatter blocks
#define BSH 7                         // bucket shift: 128 nodes per bucket
#define NBUK ((NN + 127) >> 7)        // 782 buckets
#define NH (NBUK * NBLK)              // 200192 count-matrix entries

typedef _Float16 half8 __attribute__((ext_vector_type(8)));
typedef _Float16 half4 __attribute__((ext_vector_type(4)));
typedef float f32x4 __attribute__((ext_vector_type(4)));

__device__ inline float2 unpack_h2(unsigned v) {
    union { unsigned u; _Float16 h[2]; } c; c.u = v;
    return make_float2((float)c.h[0], (float)c.h[1]);
}
__device__ inline unsigned pack_h2(float a, float b) {
    union { unsigned u; _Float16 h[2]; } c;
    c.h[0] = (_Float16)a; c.h[1] = (_Float16)b; return c.u;
}

// ============ atomic-free CSR build ============
// edge_index is int32 from harness: src = ei[e], dst = ei[NE+e].
// Bucket = dst>>7. Count matrix histM[bucket][block] -> bucket-major exclusive
// scan -> contiguous (bucket,block) segments; bucket regions contiguous.

__global__ __launch_bounds__(256) void k_hist(const int* __restrict__ ei,
                                              int* __restrict__ histM) {
    __shared__ int h[NBUK];
    for (int i = threadIdx.x; i < NBUK; i += 256) h[i] = 0;
    __syncthreads();
    int blk = blockIdx.x;
    int chunk = (NE + NBLK - 1) / NBLK;
    int beg = blk * chunk;
    int end = beg + chunk < NE ? beg + chunk : NE;
    for (int e = beg + threadIdx.x; e < end; e += 256)
        atomicAdd(&h[ei[NE + e] >> BSH], 1);           // LDS atomic
    __syncthreads();
    for (int b = threadIdx.x; b < NBUK; b += 256)
        histM[b * NBLK + blk] = h[b];
}

// inclusive scan of 512-chunks in place; block totals to partial[]
__global__ __launch_bounds__(512) void k_scan1(int* __restrict__ data,
                                               int* __restrict__ partial, int n) {
    __shared__ int s[512];
    int t = threadIdx.x;
    int i = blockIdx.x * 512 + t;
    int v = (i < n) ? data[i] : 0;
    s[t] = v;
    __syncthreads();
    #pragma unroll
    for (int off = 1; off < 512; off <<= 1) {
        int tmp = (t >= off) ? s[t - off] : 0;
        __syncthreads();
        s[t] += tmp;
        __syncthreads();
    }
    if (i < n) data[i] = s[t];
    if (t == 511) partial[blockIdx.x] = s[511];
}

__global__ void k_scanout(const int* __restrict__ incl, const int* __restrict__ partial,
                          int* __restrict__ offM, int n) {
    int i = blockIdx.x * blockDim.x + threadIdx.x;
    if (i < n) {
        int b = i >> 9;
        int off = b ? partial[b - 1] : 0;
        offM[i + 1] = incl[i] + off;
        if (i == 0) offM[0] = 0;
    }
}

// scatter edges into bucket segments; pairs packed (src<<7)|dstLocal (24 bits)
__global__ __launch_bounds__(256) void k_scatter(const int* __restrict__ ei,
                                                 const int* __restrict__ offM,
                                                 unsigned* __restrict__ pairs) {
    __shared__ int cur[NBUK];
    int blk = blockIdx.x;
    for (int b = threadIdx.x; b < NBUK; b += 256)
        cur[b] = offM[b * NBLK + blk];
    __syncthreads();
    int chunk = (NE + NBLK - 1) / NBLK;
    int beg = blk * chunk;
    int end = beg + chunk < NE ? beg + chunk : NE;
    for (int e = beg + threadIdx.x; e < end; e += 256) {
        int d = ei[NE + e];
        int s = ei[e];
        int pos = atomicAdd(&cur[d >> BSH], 1);        // LDS atomic
        pairs[pos] = ((unsigned)s << BSH) | (unsigned)(d & 127);
    }
}

// per-bucket: group edges by exact node -> csr + row_ptr
__global__ __launch_bounds__(256) void k_csr(const unsigned* __restrict__ pairs,
                                             const int* __restrict__ offM,
                                             int* __restrict__ csr,
                                             int* __restrict__ row_ptr) {
    __shared__ int cnt[128], off[129], cur[128];
    int b = blockIdx.x;
    int t = threadIdx.x;
    int ebeg = offM[b * NBLK];
    int eend = (b + 1 < NBUK) ? offM[(b + 1) * NBLK] : NE;
    if (t < 128) cnt[t] = 0;
    __syncthreads();
    for (int e = ebeg + t; e < eend; e += 256)
        atomicAdd(&cnt[pairs[e] & 127], 1);
    __syncthreads();
    if (t == 0) {
        int acc = 0;
        for (int i = 0; i < 128; ++i) { off[i] = acc; acc += cnt[i]; }
        off[128] = acc;
    }
    __syncthreads();
    if (t < 128) cur[t] = 0;
    __syncthreads();
    for (int e = ebeg + t; e < eend; e += 256) {
        unsigned p = pairs[e];
        int local = p & 127;
        int lpos = atomicAdd(&cur[local], 1);
        csr[ebeg + off[local] + lpos] = (int)(p >> BSH);
    }
    int n0 = b << BSH;
    if (t < 128 && n0 + t < NN) row_ptr[n0 + t] = ebeg + off[t];
    if (b == 0 && t == 0) row_ptr[NN] = NE;
}

// ============ weight prep: f32 -> fp16, concat [Wl;Wr] ============

__global__ void k_prep_w(const float* __restrict__ Wl1, const float* __restrict__ Wr1,
                         const float* __restrict__ Wl2, const float* __restrict__ Wr2,
                         _Float16* __restrict__ Wc1, _Float16* __restrict__ Wc2) {
    int i = blockIdx.x * 256 + threadIdx.x;
    if (i < 16384) {
        Wc1[i] = (_Float16)Wl1[i];
        Wc1[16384 + i] = (_Float16)Wr1[i];
    }
    if (i < 5120) {
        Wc2[i] = (_Float16)Wl2[i];
        Wc2[5120 + i] = (_Float16)Wr2[i];
    }
}

// ============ fp16 MFMA GEMM: C = A @ W^T, K=128 ============
// A: [M,128] f32 (A_F32=1) or fp16; W: [Ntot,128] fp16; C: [M,Ntot] fp16.

template <int A_F32>
__global__ __launch_bounds__(256) void k_gemm(const void* __restrict__ Av,
                                              const _Float16* __restrict__ W,
                                              _Float16* __restrict__ C,
                                              int M, int Ntot) {
    __shared__ _Float16 As[64][136];
    __shared__ _Float16 Ws[64][136];
    int tid = threadIdx.x;
    int m0 = blockIdx.x * 64;

    if (A_F32) {
        const float* A = (const float*)Av;
        #pragma unroll
        for (int it = 0; it < 8; ++it) {
            int idx = it * 1024 + tid * 4;
            int r = idx >> 7, c = idx & 127;
            float4 v = make_float4(0.f, 0.f, 0.f, 0.f);
            if (m0 + r < M) v = *(const float4*)&A[(size_t)(m0 + r) * 128 + c];
            half4 hv;
            hv[0] = (_Float16)v.x; hv[1] = (_Float16)v.y;
            hv[2] = (_Float16)v.z; hv[3] = (_Float16)v.w;
            *(half4*)&As[r][c] = hv;
        }
    } else {
        const _Float16* A = (const _Float16*)Av;
        #pragma unroll
        for (int it = 0; it < 4; ++it) {
            int idx = it * 2048 + tid * 8;
            int r = idx >> 7, c = idx & 127;
            half8 v = {};
            if (m0 + r < M) v = *(const half8*)&A[(size_t)(m0 + r) * 128 + c];
            *(half8*)&As[r][c] = v;
        }
    }

    int wave = tid >> 6, lane = tid & 63;
    int wm = (wave >> 1) * 32, wn = (wave & 1) * 32;
    int lrow = lane & 15, kblk = lane >> 4;

    for (int nc0 = 0; nc0 < Ntot; nc0 += 64) {
        __syncthreads();
        #pragma unroll
        for (int it = 0; it < 4; ++it) {
            int idx = it * 2048 + tid * 8;
            int r = idx >> 7, c = idx & 127;
            half8 v = {};
            if (nc0 + r < Ntot) v = *(const half8*)&W[(size_t)(nc0 + r) * 128 + c];
            *(half8*)&Ws[r][c] = v;
        }
        __syncthreads();

        f32x4 acc00 = {0.f,0.f,0.f,0.f}, acc01 = {0.f,0.f,0.f,0.f};
        f32x4 acc10 = {0.f,0.f,0.f,0.f}, acc11 = {0.f,0.f,0.f,0.f};
        #pragma unroll
        for (int ks = 0; ks < 4; ++ks) {
            half8 a0 = *(const half8*)&As[wm + lrow][ks * 32 + kblk * 8];
            half8 a1 = *(const half8*)&As[wm + 16 + lrow][ks * 32 + kblk * 8];
            half8 b0 = *(const half8*)&Ws[wn + lrow][ks * 32 + kblk * 8];
            half8 b1 = *(const half8*)&Ws[wn + 16 + lrow][ks * 32 + kblk * 8];
            acc00 = __builtin_amdgcn_mfma_f32_16x16x32_f16(a0, b0, acc00, 0, 0, 0);
            acc01 = __builtin_amdgcn_mfma_f32_16x16x32_f16(a0, b1, acc01, 0, 0, 0);
            acc10 = __builtin_amdgcn_mfma_f32_16x16x32_f16(a1, b0, acc10, 0, 0, 0);
            acc11 = __builtin_amdgcn_mfma_f32_16x16x32_f16(a1, b1, acc11, 0, 0, 0);
        }

        int rbase = kblk * 4;
        #pragma unroll
        for (int r = 0; r < 4; ++r) {
            int gr0 = m0 + wm + rbase + r;
            int gr1 = m0 + wm + 16 + rbase + r;
            int gc0 = nc0 + wn + lrow;
            int gc1 = nc0 + wn + 16 + lrow;
            if (gr0 < M && gc0 < Ntot) C[(size_t)gr0 * Ntot + gc0] = (_Float16)acc00[r];
            if (gr0 < M && gc1 < Ntot) C[(size_t)gr0 * Ntot + gc1] = (_Float16)acc01[r];
            if (gr1 < M && gc0 < Ntot) C[(size_t)gr1 * Ntot + gc0] = (_Float16)acc10[r];
            if (gr1 < M && gc1 < Ntot) C[(size_t)gr1 * Ntot + gc1] = (_Float16)acc11[r];
        }
    }
}

// ============ fused agg layer 1 ============
// tmp1: [NN][256] fp16 (xl | xr). h = relu(mean(xl[src]) + bl1 + xr), fp16.

__global__ __launch_bounds__(256) void k_agg1(const _Float16* __restrict__ tmp1,
                                              const float* __restrict__ bl1,
                                              const int* __restrict__ row_ptr,
                                              const int* __restrict__ csr,
                                              _Float16* __restrict__ h) {
    int node = blockIdx.x * 4 + (threadIdx.x >> 6);
    if (node >= NN) return;
    int lane = threadIdx.x & 63;
    int beg = row_ptr[node], end = row_ptr[node + 1];
    const unsigned* p = (const unsigned*)tmp1;
    float sx = 0.f, sy = 0.f;
    int e = beg;
    for (; e + 4 <= end; e += 4) {
        int s0 = csr[e], s1 = csr[e + 1], s2 = csr[e + 2], s3 = csr[e + 3];
        float2 f0 = unpack_h2(p[(size_t)s0 * 128 + lane]);
        float2 f1 = unpack_h2(p[(size_t)s1 * 128 + lane]);
        float2 f2 = unpack_h2(p[(size_t)s2 * 128 + lane]);
        float2 f3 = unpack_h2(p[(size_t)s3 * 128 + lane]);
        sx += (f0.x + f1.x) + (f2.x + f3.x);
        sy += (f0.y + f1.y) + (f2.y + f3.y);
    }
    for (; e < end; ++e) {
        float2 f = unpack_h2(p[(size_t)csr[e] * 128 + lane]);
        sx += f.x; sy += f.y;
    }
    int deg = end - beg;
    float inv = 1.0f / (float)(deg > 1 ? deg : 1);
    float2 xr = unpack_h2(p[(size_t)node * 128 + 64 + lane]);
    float2 b = *(const float2*)&bl1[lane * 2];
    float o0 = fmaxf(sx * inv + b.x + xr.x, 0.f);
    float o1 = fmaxf(sy * inv + b.y + xr.y, 0.f);
    ((unsigned*)h)[(size_t)node * 64 + lane] = pack_h2(o0, o1);
}

// ============ fused agg layer 2 ============
// tmp2: [NN][80] fp16 (hl | hr). out = mean(hl[src]) + bl2 + hr, f32.
// 2 nodes per wave; edge loop 4-way unrolled for MLP (R7 PMC: agg2 was
// latency-bound at ~1 outstanding gather/wave, 1.5 TB/s, VALUBusy 14%).

__global__ __launch_bounds__(256) void k_agg2(const _Float16* __restrict__ tmp2,
                                              const float* __restrict__ bl2,
                                              const int* __restrict__ row_ptr,
                                              const int* __restrict__ csr,
                                              float* __restrict__ out) {
    int tid = threadIdx.x;
    int wave = tid >> 6, lane = tid & 63;
    int hw = lane >> 5, ln = lane & 31;
    int node = blockIdx.x * 8 + wave * 2 + hw;
    bool act = (node < NN) && (ln < 20);
    int beg = 0, end = 0;
    if (node < NN) { beg = row_ptr[node]; end = row_ptr[node + 1]; }
    const unsigned* p = (const unsigned*)tmp2;
    float sx = 0.f, sy = 0.f;
    int e = beg;
    for (; e + 4 <= end; e += 4) {
        int s0 = csr[e], s1 = csr[e + 1], s2 = csr[e + 2], s3 = csr[e + 3];
        if (act) {
            float2 f0 = unpack_h2(p[(size_t)s0 * 40 + ln]);
            float2 f1 = unpack_h2(p[(size_t)s1 * 40 + ln]);
            float2 f2 = unpack_h2(p[(size_t)s2 * 40 + ln]);
            float2 f3 = unpack_h2(p[(size_t)s3 * 40 + ln]);
            sx += (f0.x + f1.x) + (f2.x + f3.x);
            sy += (f0.y + f1.y) + (f2.y + f3.y);
        }
    }
    for (; e < end; ++e) {
        int s = csr[e];
        if (act) {
            float2 f = unpack_h2(p[(size_t)s * 40 + ln]);
            sx += f.x; sy += f.y;
        }
    }
    if (act) {
        int deg = end - beg;
        float inv = 1.0f / (float)(deg > 1 ? deg : 1);
        float2 hr = unpack_h2(p[(size_t)node * 40 + 20 + ln]);
        float2 b = *(const float2*)&bl2[ln * 2];
        float2 o;
        o.x = sx * inv + b.x + hr.x;
        o.y = sy * inv + b.y + hr.y;
        *(float2*)&out[(size_t)node * 40 + ln * 2] = o;
    }
}

// ============ launch ============

extern "C" void kernel_launch(void* const* d_in, const int* in_sizes, int n_in,
                              void* d_out, int out_size, void* d_ws, size_t ws_size,
                              hipStream_t stream) {
    const float* x   = (const float*)d_in[0];
    const int* ei    = (const int*)d_in[1];   // int32 (harness converts ints)
    const float* Wl1 = (const float*)d_in[2];
    const float* bl1 = (const float*)d_in[3];
    const float* Wr1 = (const float*)d_in[4];
    const float* Wl2 = (const float*)d_in[5];
    const float* bl2 = (const float*)d_in[6];
    const float* Wr2 = (const float*)d_in[7];
    float* out = (float*)d_out;

    char* ws = (char*)d_ws;
    size_t off = 0;
    auto alloc = [&](size_t bytes) -> char* {
        char* pp = ws + off;
        off = (off + bytes + 511) & ~(size_t)511;
        return pp;
    };
    int* histM      = (int*)alloc((size_t)NH * 4);
    int* offM       = (int*)alloc((size_t)(NH + 1) * 4);
    int* partial    = (int*)alloc(1024 * 4);
    int* partial2   = (int*)alloc(1024 * 4);
    unsigned* pairs = (unsigned*)alloc((size_t)NE * 4);
    int* csr        = (int*)alloc((size_t)NE * 4);
    int* row_ptr    = (int*)alloc((size_t)(NN + 1) * 4);
    _Float16* Wc1   = (_Float16*)alloc((size_t)256 * 128 * 2);
    _Float16* Wc2   = (_Float16*)alloc((size_t)80 * 128 * 2);
    _Float16* tmp1  = (_Float16*)alloc((size_t)NN * 256 * 2);
    _Float16* h     = (_Float16*)alloc((size_t)NN * 128 * 2);
    _Float16* tmp2  = (_Float16*)alloc((size_t)NN * 80 * 2);
    if (off > ws_size) return;

    // CSR build (no global atomics)
    k_hist<<<NBLK, 256, 0, stream>>>(ei, histM);
    int NSB = (NH + 511) / 512;                       // 391
    k_scan1<<<NSB, 512, 0, stream>>>(histM, partial, NH);
    k_scan1<<<1, 512, 0, stream>>>(partial, partial2, NSB);
    k_scanout<<<(NH + 255) / 256, 256, 0, stream>>>(histM, partial, offM, NH);
    k_scatter<<<NBLK, 256, 0, stream>>>(ei, offM, pairs);
    k_csr<<<NBUK, 256, 0, stream>>>(pairs, offM, csr, row_ptr);

    // weights -> fp16 concat
    k_prep_w<<<64, 256, 0, stream>>>(Wl1, Wr1, Wl2, Wr2, Wc1, Wc2);

    int gm = (NN + 63) / 64;
    // layer 1: tmp1 = x @ [Wl1;Wr1]^T  (K=128, N=256)
    k_gemm<1><<<gm, 256, 0, stream>>>(x, Wc1, tmp1, NN, 256);
    // h = relu(mean(xl[src]) + bl1 + xr)
    k_agg1<<<(NN + 3) / 4, 256, 0, stream>>>(tmp1, bl1, row_ptr, csr, h);
    // layer 2: tmp2 = h @ [Wl2;Wr2]^T  (K=128, N=80)
    k_gemm<0><<<gm, 256, 0, stream>>>(h, Wc2, tmp2, NN, 80);
    // out = mean(hl[src]) + bl2 + hr
    k_agg2<<<(NN + 7) / 8, 256, 0, stream>>>(tmp2, bl2, row_ptr, csr, out);
}